// Round 1
// baseline (367.013 us; speedup 1.0000x reference)
//
#include <hip/hip_runtime.h>

// SmoothQuant linear for M=32768, K=1024, N=1024 (K must be 1024: 256 thr × 4 cols)
// Pipeline: colmax(x), colmax(w) -> smooth scales -> row-quant w, row-quant x (int8)
//           -> i8 MFMA GEMM (exact i32 accumulate) + dequant/bias epilogue (f32 out)

typedef int v4i __attribute__((ext_vector_type(4)));

__device__ __forceinline__ void gld_lds16(const void* g, void* l) {
    __builtin_amdgcn_global_load_lds(
        (const __attribute__((address_space(1))) void*)g,
        (__attribute__((address_space(3))) void*)l,
        16, 0, 0);
}

// ---------------- column abs-max (over rows) into u32-bitcast float maxes ------------
__global__ __launch_bounds__(256) void colmax_kernel(const float* __restrict__ src,
                                                     int rows, int rpb, int K,
                                                     unsigned* __restrict__ cmax) {
    const int c = threadIdx.x * 4;          // 256 threads cover K=1024
    int r0 = blockIdx.x * rpb;
    int r1 = r0 + rpb; if (r1 > rows) r1 = rows;
    float m0 = 0.f, m1 = 0.f, m2 = 0.f, m3 = 0.f;
    const float* p = src + (size_t)r0 * K + c;
#pragma unroll 4
    for (int r = r0; r < r1; ++r, p += K) {
        float4 v = *(const float4*)p;
        m0 = fmaxf(m0, fabsf(v.x));
        m1 = fmaxf(m1, fabsf(v.y));
        m2 = fmaxf(m2, fabsf(v.z));
        m3 = fmaxf(m3, fabsf(v.w));
    }
    // non-negative floats order-preserve as unsigned bit patterns
    atomicMax(cmax + c + 0, __float_as_uint(m0));
    atomicMax(cmax + c + 1, __float_as_uint(m1));
    atomicMax(cmax + c + 2, __float_as_uint(m2));
    atomicMax(cmax + c + 3, __float_as_uint(m3));
}

// ---------------- smooth scale: s = sqrt(max(in_max*w_max, 1e-12)); inv = 1/s --------
__global__ void scale_kernel(const unsigned* __restrict__ in_max,
                             const unsigned* __restrict__ w_max,
                             float* __restrict__ smooth, float* __restrict__ inv_s, int K) {
    int k = blockIdx.x * blockDim.x + threadIdx.x;
    if (k < K) {
        float p = __uint_as_float(in_max[k]) * __uint_as_float(w_max[k]);
        float s = sqrtf(fmaxf(p, 1e-12f));
        smooth[k] = s;
        inv_s[k]  = 1.0f / s;   // IEEE divide, matches numpy 1.0/smooth
    }
}

// ---------------- per-row int8 quantization: xs = src*colscale; rs = max|xs|/127 -----
__global__ __launch_bounds__(256) void quant_rows_kernel(const float* __restrict__ src,
                                                         const float* __restrict__ colscale,
                                                         signed char* __restrict__ q,
                                                         float* __restrict__ rowscale, int K) {
    const int row = blockIdx.x;
    const int t = threadIdx.x;
    const float* srow = src + (size_t)row * K;
    float4 v  = *(const float4*)(srow + t * 4);
    float4 cs = *(const float4*)(colscale + t * 4);
    float xs0 = v.x * cs.x, xs1 = v.y * cs.y, xs2 = v.z * cs.z, xs3 = v.w * cs.w;
    float mv = fmaxf(fmaxf(fabsf(xs0), fabsf(xs1)), fmaxf(fabsf(xs2), fabsf(xs3)));
    // reduce max over 256 threads
#pragma unroll
    for (int off = 32; off > 0; off >>= 1)
        mv = fmaxf(mv, __shfl_xor(mv, off, 64));
    __shared__ float sm[4];
    if ((t & 63) == 0) sm[t >> 6] = mv;
    __syncthreads();
    mv = fmaxf(fmaxf(sm[0], sm[1]), fmaxf(sm[2], sm[3]));
    float rs = fmaxf(mv / 127.0f, 1e-12f);      // IEEE divide, matches numpy
    float q0 = fminf(fmaxf(rintf(xs0 / rs), -127.f), 127.f);
    float q1 = fminf(fmaxf(rintf(xs1 / rs), -127.f), 127.f);
    float q2 = fminf(fmaxf(rintf(xs2 / rs), -127.f), 127.f);
    float q3 = fminf(fmaxf(rintf(xs3 / rs), -127.f), 127.f);
    int b0 = (int)q0, b1 = (int)q1, b2 = (int)q2, b3 = (int)q3;
    unsigned packed = (unsigned)(b0 & 0xff) | ((unsigned)(b1 & 0xff) << 8)
                    | ((unsigned)(b2 & 0xff) << 16) | ((unsigned)(b3 & 0xff) << 24);
    *(unsigned*)(q + (size_t)row * K + t * 4) = packed;
    if (t == 0) rowscale[row] = rs;
}

// ---------------- i8 GEMM: out[m,n] = acc(i32) * x_s[m] * w_s[n] + bias[n] -----------
// 128x128 tile, BK=64, 4 waves 2x2, each wave 64x64 via 4x4 grid of 16x16x64 MFMAs.
__global__ __launch_bounds__(256) void gemm_i8_kernel(
    const signed char* __restrict__ Aq,   // [M,K]
    const signed char* __restrict__ Bq,   // [N,K]
    const float* __restrict__ xs,         // [M]
    const float* __restrict__ wsc,        // [N]
    const float* __restrict__ bias,       // [N]
    float* __restrict__ out,              // [M,N] f32
    int M, int N, int K) {
    __shared__ __align__(16) signed char As[128 * 64];
    __shared__ __align__(16) signed char Bs[128 * 64];

    const int tid  = threadIdx.x;
    const int lane = tid & 63;
    const int wave = tid >> 6;
    const int waveM = (wave >> 1) * 64;
    const int waveN = (wave & 1) * 64;
    const int bm = blockIdx.y * 128;
    const int bn = blockIdx.x * 128;

    // staging: thread t loads 16B; per wave LDS dest = base + lane*16 (wave-uniform rule)
    const int srow  = tid >> 2;        // 0..63
    const int sbyte = (tid & 3) * 16;  // 0,16,32,48

    const signed char* aG0 = Aq + (size_t)(bm + srow) * K + sbyte;
    const signed char* aG1 = Aq + (size_t)(bm + 64 + srow) * K + sbyte;
    const signed char* bG0 = Bq + (size_t)(bn + srow) * K + sbyte;
    const signed char* bG1 = Bq + (size_t)(bn + 64 + srow) * K + sbyte;
    signed char* aL0 = As + srow * 64 + sbyte;
    signed char* aL1 = As + (64 + srow) * 64 + sbyte;
    signed char* bL0 = Bs + srow * 64 + sbyte;
    signed char* bL1 = Bs + (64 + srow) * 64 + sbyte;

    v4i acc[4][4] = {};

    const int fr = lane & 15;          // row within 16x16 frag
    const int fq = (lane >> 4) * 16;   // k-byte offset of this lane's 16B chunk

    for (int k0 = 0; k0 < K; k0 += 64) {
        __syncthreads();
        gld_lds16(aG0 + k0, aL0);
        gld_lds16(aG1 + k0, aL1);
        gld_lds16(bG0 + k0, bL0);
        gld_lds16(bG1 + k0, bL1);
        __syncthreads();

        v4i af[4], bf[4];
#pragma unroll
        for (int i = 0; i < 4; ++i)
            af[i] = *(const v4i*)(As + (waveM + i * 16 + fr) * 64 + fq);
#pragma unroll
        for (int j = 0; j < 4; ++j)
            bf[j] = *(const v4i*)(Bs + (waveN + j * 16 + fr) * 64 + fq);
#pragma unroll
        for (int i = 0; i < 4; ++i)
#pragma unroll
            for (int j = 0; j < 4; ++j)
                acc[i][j] = __builtin_amdgcn_mfma_i32_16x16x64_i8(af[i], bf[j], acc[i][j], 0, 0, 0);
    }

    // epilogue: C/D layout col=lane&15, row=(lane>>4)*4+reg (16x16 family)
    const int orow0 = bm + waveM + (lane >> 4) * 4;
    const int ocol0 = bn + waveN + fr;
#pragma unroll
    for (int j = 0; j < 4; ++j) {
        const int col = ocol0 + j * 16;
        const float wn = wsc[col];
        const float bv = bias[col];
#pragma unroll
        for (int i = 0; i < 4; ++i) {
            const int rbase = orow0 + i * 16;
#pragma unroll
            for (int r = 0; r < 4; ++r) {
                const int row = rbase + r;
                float v = (float)acc[i][j][r] * xs[row];
                out[(size_t)row * N + col] = v * wn + bv;
            }
        }
    }
}

extern "C" void kernel_launch(void* const* d_in, const int* in_sizes, int n_in,
                              void* d_out, int out_size, void* d_ws, size_t ws_size,
                              hipStream_t stream) {
    const float* x    = (const float*)d_in[0];
    const float* w    = (const float*)d_in[1];
    const float* bias = (const float*)d_in[2];
    float* out = (float*)d_out;

    const int N = in_sizes[2];            // 1024
    const int K = in_sizes[1] / N;        // 1024
    const int M = in_sizes[0] / K;        // 32768

    char* ws = (char*)d_ws;
    unsigned* in_max = (unsigned*)(ws);
    unsigned* w_max  = (unsigned*)(ws + 4096);
    float* smooth    = (float*)(ws + 8192);
    float* inv_s     = (float*)(ws + 12288);
    float* w_s       = (float*)(ws + 16384);
    float* x_s       = (float*)(ws + 20480);
    size_t xq_off    = 20480 + (((size_t)M * 4 + 255) / 256) * 256;
    signed char* x_q = (signed char*)(ws + xq_off);
    signed char* w_q = x_q + (size_t)M * K;

    hipMemsetAsync(d_ws, 0, 8192, stream);  // zero in_max/w_max (0u == 0.0f)

    {   // col abs-max of |x| over M rows
        int rpb = 64; int nb = (M + rpb - 1) / rpb;      // 512 blocks
        colmax_kernel<<<nb, 256, 0, stream>>>(x, M, rpb, K, in_max);
    }
    {   // col abs-max of |w| over N rows
        int rpb = 64; int nb = (N + rpb - 1) / rpb;      // 16 blocks
        colmax_kernel<<<nb, 256, 0, stream>>>(w, N, rpb, K, w_max);
    }
    scale_kernel<<<(K + 255) / 256, 256, 0, stream>>>(in_max, w_max, smooth, inv_s, K);
    quant_rows_kernel<<<N, 256, 0, stream>>>(w, smooth, w_q, w_s, K);
    quant_rows_kernel<<<M, 256, 0, stream>>>(x, inv_s, x_q, x_s, K);

    dim3 grid(N / 128, M / 128);  // x = N fastest for A-tile L2 reuse
    gemm_i8_kernel<<<grid, 256, 0, stream>>>(x_q, w_q, x_s, w_s, bias, out, M, N, K);
}

// Round 2
// 338.458 us; speedup vs baseline: 1.0844x; 1.0844x over previous
//
#include <hip/hip_runtime.h>

// SmoothQuant linear, M=32768, K=1024, N=1024.
// Phases: colmax partials (x, w) -> 2nd-stage partial -> finalize scales
//         -> wave-per-row int8 quant (w, x) -> i8 MFMA GEMM + dequant epilogue.

typedef int v4i __attribute__((ext_vector_type(4)));

__device__ __forceinline__ void gld_lds16(const void* g, void* l) {
    __builtin_amdgcn_global_load_lds(
        (const __attribute__((address_space(1))) void*)g,
        (__attribute__((address_space(3))) void*)l,
        16, 0, 0);
}

// ---- stage-1/2 column abs-max partials: partial[b][k] = max_{rows in block} |src| ----
__global__ __launch_bounds__(256) void colmax_part_kernel(const float* __restrict__ src,
                                                          int rows, int rpb, int K,
                                                          float* __restrict__ partial) {
    const int c = threadIdx.x * 4;          // 256 threads cover K=1024
    int r0 = blockIdx.x * rpb;
    int r1 = r0 + rpb; if (r1 > rows) r1 = rows;
    float m0 = 0.f, m1 = 0.f, m2 = 0.f, m3 = 0.f;
    const float* p = src + (size_t)r0 * K + c;
#pragma unroll 4
    for (int r = r0; r < r1; ++r, p += K) {
        float4 v = *(const float4*)p;
        m0 = fmaxf(m0, fabsf(v.x));
        m1 = fmaxf(m1, fabsf(v.y));
        m2 = fmaxf(m2, fabsf(v.z));
        m3 = fmaxf(m3, fabsf(v.w));
    }
    float4 o; o.x = m0; o.y = m1; o.z = m2; o.w = m3;
    *(float4*)(partial + (size_t)blockIdx.x * K + c) = o;
}

// ---- finalize: reduce small partials, smooth = sqrt(max(mx*mw,eps)), inv = 1/smooth --
__global__ void finalize_kernel(const float* __restrict__ px, int nx,
                                const float* __restrict__ pw, int nw,
                                float* __restrict__ smooth, float* __restrict__ inv_s, int K) {
    int c = blockIdx.x * blockDim.x + threadIdx.x;
    if (c >= K) return;
    float mx = 0.f, mw = 0.f;
    for (int r = 0; r < nx; ++r) mx = fmaxf(mx, px[(size_t)r * K + c]);
    for (int r = 0; r < nw; ++r) mw = fmaxf(mw, pw[(size_t)r * K + c]);
    float s = sqrtf(fmaxf(mx * mw, 1e-12f));
    smooth[c] = s;
    inv_s[c]  = 1.0f / s;   // IEEE divide, matches numpy 1.0/smooth
}

// ---- wave-per-row int8 quant: xs = src*colscale; rs = max(|xs|)/127; q = clip(rint) --
// K must be 1024. 4 waves/block, one row per wave, no __syncthreads.
__global__ __launch_bounds__(256) void quant_rows_wave_kernel(
    const float* __restrict__ src, const float* __restrict__ colscale,
    signed char* __restrict__ q, float* __restrict__ rowscale, int K) {
    const int wave = threadIdx.x >> 6, lane = threadIdx.x & 63;
    const int row = blockIdx.x * 4 + wave;
    const float* srow = src + (size_t)row * K;
    float xs[16];
    float mv = 0.f;
#pragma unroll
    for (int i = 0; i < 4; ++i) {
        float4 v  = *(const float4*)(srow + i * 256 + lane * 4);
        float4 cs = *(const float4*)(colscale + i * 256 + lane * 4);
        xs[i*4+0] = v.x * cs.x; xs[i*4+1] = v.y * cs.y;
        xs[i*4+2] = v.z * cs.z; xs[i*4+3] = v.w * cs.w;
        mv = fmaxf(mv, fmaxf(fmaxf(fabsf(xs[i*4+0]), fabsf(xs[i*4+1])),
                             fmaxf(fabsf(xs[i*4+2]), fabsf(xs[i*4+3]))));
    }
#pragma unroll
    for (int off = 32; off > 0; off >>= 1)
        mv = fmaxf(mv, __shfl_xor(mv, off, 64));
    const float rs = fmaxf(mv / 127.0f, 1e-12f);   // IEEE divide
    signed char* qrow = q + (size_t)row * K;
#pragma unroll
    for (int i = 0; i < 4; ++i) {
        float q0 = fminf(fmaxf(rintf(xs[i*4+0] / rs), -127.f), 127.f);
        float q1 = fminf(fmaxf(rintf(xs[i*4+1] / rs), -127.f), 127.f);
        float q2 = fminf(fmaxf(rintf(xs[i*4+2] / rs), -127.f), 127.f);
        float q3 = fminf(fmaxf(rintf(xs[i*4+3] / rs), -127.f), 127.f);
        int b0 = (int)q0, b1 = (int)q1, b2 = (int)q2, b3 = (int)q3;
        unsigned packed = (unsigned)(b0 & 0xff) | ((unsigned)(b1 & 0xff) << 8)
                        | ((unsigned)(b2 & 0xff) << 16) | ((unsigned)(b3 & 0xff) << 24);
        *(unsigned*)(qrow + i * 256 + lane * 4) = packed;
    }
    if (lane == 0) rowscale[row] = rs;
}

// ---- i8 GEMM: out[m,n] = i32acc * x_s[m] * w_s[n] + bias[n] -------------------------
// 128x128 tile, BK=64, 4 waves 2x2. XOR-swizzled LDS (kills 8-way bank conflicts),
// XCD-stripe block mapping (A-stripe 4MB + B 1MB fit per-XCD L2).
__global__ __launch_bounds__(256) void gemm_i8_kernel(
    const signed char* __restrict__ Aq,   // [M,K]
    const signed char* __restrict__ Bq,   // [N,K]
    const float* __restrict__ xs,         // [M]
    const float* __restrict__ wsc,        // [N]
    const float* __restrict__ bias,       // [N]
    float* __restrict__ out,              // [M,N] f32
    int M, int N, int K) {
    __shared__ __align__(16) signed char As[128 * 64];
    __shared__ __align__(16) signed char Bs[128 * 64];

    const int tid  = threadIdx.x;
    const int lane = tid & 63;
    const int wave = tid >> 6;
    const int waveM = (wave >> 1) * 64;
    const int waveN = (wave & 1) * 64;

    // XCD-stripe swizzle: xcd = bid&7 owns M-tiles [xcd*32, xcd*32+32), n fastest.
    const int bid = blockIdx.x;
    const int tile_m = (bid & 7) * 32 + (bid >> 6);
    const int tile_n = (bid >> 3) & 7;
    const int bm = tile_m * 128;
    const int bn = tile_n * 128;

    // staging: thread t -> LDS slot (srow, qslot); global chunk = qslot ^ ((srow>>1)&3)
    const int srow  = tid >> 2;                               // 0..63
    const int qslot = tid & 3;
    const int gq    = (qslot ^ ((srow >> 1) & 3)) * 16;       // global byte offset
    const int lbyte = qslot * 16;                             // LDS byte offset in row

    const signed char* aG0 = Aq + (size_t)(bm + srow) * K + gq;
    const signed char* aG1 = Aq + (size_t)(bm + 64 + srow) * K + gq;   // (64+srow)>>1&3 same
    const signed char* bG0 = Bq + (size_t)(bn + srow) * K + gq;
    const signed char* bG1 = Bq + (size_t)(bn + 64 + srow) * K + gq;
    signed char* aL0 = As + srow * 64 + lbyte;
    signed char* aL1 = As + (64 + srow) * 64 + lbyte;
    signed char* bL0 = Bs + srow * 64 + lbyte;
    signed char* bL1 = Bs + (64 + srow) * 64 + lbyte;

    v4i acc[4][4] = {};

    const int fr = lane & 15;                                 // row within 16-row group
    const int fp = (((lane >> 4) ^ ((fr >> 1) & 3))) * 16;    // swizzled chunk position

    for (int k0 = 0; k0 < K; k0 += 64) {
        __syncthreads();
        gld_lds16(aG0 + k0, aL0);
        gld_lds16(aG1 + k0, aL1);
        gld_lds16(bG0 + k0, bL0);
        gld_lds16(bG1 + k0, bL1);
        __syncthreads();

        v4i af[4], bf[4];
#pragma unroll
        for (int i = 0; i < 4; ++i)
            af[i] = *(const v4i*)(As + (waveM + i * 16 + fr) * 64 + fp);
#pragma unroll
        for (int j = 0; j < 4; ++j)
            bf[j] = *(const v4i*)(Bs + (waveN + j * 16 + fr) * 64 + fp);
#pragma unroll
        for (int i = 0; i < 4; ++i)
#pragma unroll
            for (int j = 0; j < 4; ++j)
                acc[i][j] = __builtin_amdgcn_mfma_i32_16x16x64_i8(af[i], bf[j], acc[i][j], 0, 0, 0);
    }

    // epilogue: C/D layout col=lane&15, row=(lane>>4)*4+reg (16x16 family)
    const int orow0 = bm + waveM + (lane >> 4) * 4;
    const int ocol0 = bn + waveN + fr;
#pragma unroll
    for (int j = 0; j < 4; ++j) {
        const int col = ocol0 + j * 16;
        const float wn = wsc[col];
        const float bv = bias[col];
#pragma unroll
        for (int i = 0; i < 4; ++i) {
            const int rbase = orow0 + i * 16;
#pragma unroll
            for (int r = 0; r < 4; ++r) {
                const int row = rbase + r;
                float v = (float)acc[i][j][r] * xs[row];
                out[(size_t)row * N + col] = v * wn + bv;
            }
        }
    }
}

extern "C" void kernel_launch(void* const* d_in, const int* in_sizes, int n_in,
                              void* d_out, int out_size, void* d_ws, size_t ws_size,
                              hipStream_t stream) {
    const float* x    = (const float*)d_in[0];
    const float* w    = (const float*)d_in[1];
    const float* bias = (const float*)d_in[2];
    float* out = (float*)d_out;

    const int N = in_sizes[2];            // 1024
    const int K = in_sizes[1] / N;        // 1024
    const int M = in_sizes[0] / K;        // 32768

    char* ws = (char*)d_ws;
    float* p1x       = (float*)(ws);                    // 512 x K   (2 MB)
    float* p2x       = (float*)(ws + 2097152);          // 16 x K    (64 KB)
    float* pw        = (float*)(ws + 2162688);          // 16 x K    (64 KB)
    float* smooth    = (float*)(ws + 2228224);          // K
    float* inv_s     = (float*)(ws + 2232320);          // K
    float* w_s       = (float*)(ws + 2236416);          // N
    float* x_s       = (float*)(ws + 2240512);          // M  (128 KB)
    signed char* x_q = (signed char*)(ws + 2371584);    // M*K (32 MB)
    signed char* w_q = x_q + (size_t)M * K;             // N*K (1 MB)

    // stage-1 col abs-max of x: 512 blocks x 64 rows
    colmax_part_kernel<<<512, 256, 0, stream>>>(x, M, 64, K, p1x);
    // stage-2: reduce 512 partial rows -> 16
    colmax_part_kernel<<<16, 256, 0, stream>>>(p1x, 512, 32, K, p2x);
    // col abs-max of w: 16 blocks x 64 rows
    colmax_part_kernel<<<16, 256, 0, stream>>>(w, N, 64, K, pw);
    // smooth scales
    finalize_kernel<<<(K + 255) / 256, 256, 0, stream>>>(p2x, 16, pw, 16, smooth, inv_s, K);
    // quantize weights (N rows) and activations (M rows), one wave per row
    quant_rows_wave_kernel<<<N / 4, 256, 0, stream>>>(w, smooth, w_q, w_s, K);
    quant_rows_wave_kernel<<<M / 4, 256, 0, stream>>>(x, inv_s, x_q, x_s, K);
    // GEMM
    gemm_i8_kernel<<<(M / 128) * (N / 128), 256, 0, stream>>>(x_q, w_q, x_s, w_s, bias, out, M, N, K);
}

// Round 3
// 335.786 us; speedup vs baseline: 1.0930x; 1.0080x over previous
//
#include <hip/hip_runtime.h>

// SmoothQuant linear, M=32768, K=1024, N=1024.
// colmax partials (x, w) -> stage2 -> finalize scales -> wave-per-row int8 quant
// -> i8 MFMA GEMM (double-buffered LDS pipeline) + dequant epilogue.

typedef int v4i __attribute__((ext_vector_type(4)));

__device__ __forceinline__ void gld_lds16(const void* g, void* l) {
    __builtin_amdgcn_global_load_lds(
        (const __attribute__((address_space(1))) void*)g,
        (__attribute__((address_space(3))) void*)l,
        16, 0, 0);
}

// ---- column abs-max partials: partial[b][k] = max_{rows in block} |src[r][k]| -------
__global__ __launch_bounds__(256) void colmax_part_kernel(const float* __restrict__ src,
                                                          int rows, int rpb, int K,
                                                          float* __restrict__ partial) {
    const int c = threadIdx.x * 4;          // 256 threads cover K=1024
    int r0 = blockIdx.x * rpb;
    int r1 = r0 + rpb; if (r1 > rows) r1 = rows;
    float m0 = 0.f, m1 = 0.f, m2 = 0.f, m3 = 0.f;
    const float* p = src + (size_t)r0 * K + c;
#pragma unroll 8
    for (int r = r0; r < r1; ++r, p += K) {
        float4 v = *(const float4*)p;
        m0 = fmaxf(m0, fabsf(v.x));
        m1 = fmaxf(m1, fabsf(v.y));
        m2 = fmaxf(m2, fabsf(v.z));
        m3 = fmaxf(m3, fabsf(v.w));
    }
    float4 o; o.x = m0; o.y = m1; o.z = m2; o.w = m3;
    *(float4*)(partial + (size_t)blockIdx.x * K + c) = o;
}

// ---- finalize: smooth = sqrt(max(mx*mw, eps)); inv = 1/smooth (IEEE) ----------------
__global__ void finalize_kernel(const float* __restrict__ px, int nx,
                                const float* __restrict__ pw, int nw,
                                float* __restrict__ smooth, float* __restrict__ inv_s, int K) {
    int c = blockIdx.x * blockDim.x + threadIdx.x;
    if (c >= K) return;
    float mx = 0.f, mw = 0.f;
    for (int r = 0; r < nx; ++r) mx = fmaxf(mx, px[(size_t)r * K + c]);
    for (int r = 0; r < nw; ++r) mw = fmaxf(mw, pw[(size_t)r * K + c]);
    float s = sqrtf(fmaxf(mx * mw, 1e-12f));
    smooth[c] = s;
    inv_s[c]  = 1.0f / s;
}

// ---- wave-per-row int8 quant: 16 contiguous cols per lane, one dwordx4 store --------
// K must be 1024. 4 waves/block, one row per wave, no __syncthreads.
__global__ __launch_bounds__(256) void quant_rows_wave_kernel(
    const float* __restrict__ src, const float* __restrict__ colscale,
    signed char* __restrict__ q, float* __restrict__ rowscale, int K) {
    const int wave = threadIdx.x >> 6, lane = threadIdx.x & 63;
    const int row = blockIdx.x * 4 + wave;
    const float* srow = src + (size_t)row * K + lane * 16;
    const float* crow = colscale + lane * 16;
    float xs[16];
    float mv = 0.f;
#pragma unroll
    for (int i = 0; i < 4; ++i) {
        float4 v  = *(const float4*)(srow + i * 4);
        float4 cs = *(const float4*)(crow + i * 4);
        xs[i*4+0] = v.x * cs.x; xs[i*4+1] = v.y * cs.y;
        xs[i*4+2] = v.z * cs.z; xs[i*4+3] = v.w * cs.w;
        mv = fmaxf(mv, fmaxf(fmaxf(fabsf(xs[i*4+0]), fabsf(xs[i*4+1])),
                             fmaxf(fabsf(xs[i*4+2]), fabsf(xs[i*4+3]))));
    }
#pragma unroll
    for (int off = 32; off > 0; off >>= 1)
        mv = fmaxf(mv, __shfl_xor(mv, off, 64));
    const float rs = fmaxf(mv / 127.0f, 1e-12f);   // IEEE divide, matches numpy
    unsigned pk[4];
#pragma unroll
    for (int i = 0; i < 4; ++i) {
        float q0 = fminf(fmaxf(rintf(xs[i*4+0] / rs), -127.f), 127.f);  // IEEE divides
        float q1 = fminf(fmaxf(rintf(xs[i*4+1] / rs), -127.f), 127.f);
        float q2 = fminf(fmaxf(rintf(xs[i*4+2] / rs), -127.f), 127.f);
        float q3 = fminf(fmaxf(rintf(xs[i*4+3] / rs), -127.f), 127.f);
        int b0 = (int)q0, b1 = (int)q1, b2 = (int)q2, b3 = (int)q3;
        pk[i] = (unsigned)(b0 & 0xff) | ((unsigned)(b1 & 0xff) << 8)
              | ((unsigned)(b2 & 0xff) << 16) | ((unsigned)(b3 & 0xff) << 24);
    }
    *(uint4*)(q + (size_t)row * K + lane * 16) = make_uint4(pk[0], pk[1], pk[2], pk[3]);
    if (lane == 0) rowscale[row] = rs;
}

// ---- i8 GEMM: out[m,n] = i32acc * x_s[m] * w_s[n] + bias[n] -------------------------
// 128x128 tile, BK=64, 4 waves 2x2, double-buffered LDS (one barrier per K-step,
// prefetch overlaps MFMA). XOR-swizzled LDS; XCD-stripe block mapping.
__global__ __launch_bounds__(256) void gemm_i8_kernel(
    const signed char* __restrict__ Aq,   // [M,K]
    const signed char* __restrict__ Bq,   // [N,K]
    const float* __restrict__ xs,         // [M]
    const float* __restrict__ wsc,        // [N]
    const float* __restrict__ bias,       // [N]
    float* __restrict__ out,              // [M,N] f32
    int M, int N, int K) {
    __shared__ __align__(16) signed char As[2][128 * 64];
    __shared__ __align__(16) signed char Bs[2][128 * 64];

    const int tid  = threadIdx.x;
    const int lane = tid & 63;
    const int wave = tid >> 6;
    const int waveM = (wave >> 1) * 64;
    const int waveN = (wave & 1) * 64;

    // XCD-stripe swizzle: xcd = bid&7 owns M-tiles [xcd*32, xcd*32+32), n fastest.
    const int bid = blockIdx.x;
    const int bm = ((bid & 7) * 32 + (bid >> 6)) * 128;
    const int bn = ((bid >> 3) & 7) * 128;

    // staging: thread t -> LDS slot (srow, qslot); global chunk = qslot ^ ((srow>>1)&3)
    const int srow  = tid >> 2;                               // 0..63
    const int qslot = tid & 3;
    const int gq    = (qslot ^ ((srow >> 1) & 3)) * 16;       // global byte offset
    const int ldsOff = srow * 64 + qslot * 16;                // == wave_base + lane*16

    const signed char* aG0 = Aq + (size_t)(bm + srow) * K + gq;
    const signed char* aG1 = Aq + (size_t)(bm + 64 + srow) * K + gq;
    const signed char* bG0 = Bq + (size_t)(bn + srow) * K + gq;
    const signed char* bG1 = Bq + (size_t)(bn + 64 + srow) * K + gq;

    v4i acc[4][4] = {};

    const int fr = lane & 15;                                 // row within 16-row group
    const int fp = ((lane >> 4) ^ ((fr >> 1) & 3)) * 16;      // swizzled chunk position

#define STAGE(k0, b)                                   \
    do {                                               \
        gld_lds16(aG0 + (k0), &As[b][ldsOff]);         \
        gld_lds16(aG1 + (k0), &As[b][ldsOff + 4096]);  \
        gld_lds16(bG0 + (k0), &Bs[b][ldsOff]);         \
        gld_lds16(bG1 + (k0), &Bs[b][ldsOff + 4096]);  \
    } while (0)

#define COMPUTE(b)                                                        \
    do {                                                                  \
        v4i af[4], bf[4];                                                 \
        _Pragma("unroll")                                                 \
        for (int i = 0; i < 4; ++i)                                       \
            af[i] = *(const v4i*)&As[b][(waveM + i * 16 + fr) * 64 + fp]; \
        _Pragma("unroll")                                                 \
        for (int j = 0; j < 4; ++j)                                       \
            bf[j] = *(const v4i*)&Bs[b][(waveN + j * 16 + fr) * 64 + fp]; \
        _Pragma("unroll")                                                 \
        for (int i = 0; i < 4; ++i)                                       \
            _Pragma("unroll")                                             \
            for (int j = 0; j < 4; ++j)                                   \
                acc[i][j] = __builtin_amdgcn_mfma_i32_16x16x64_i8(        \
                    af[i], bf[j], acc[i][j], 0, 0, 0);                    \
    } while (0)

    STAGE(0, 0);
    for (int k0 = 0; k0 < K; k0 += 128) {
        __syncthreads();                       // buf0 staged; prior reads of buf1 done
        if (k0 + 64 < K) STAGE(k0 + 64, 1);    // prefetch overlaps compute below
        COMPUTE(0);
        __syncthreads();                       // buf1 staged; prior reads of buf0 done
        if (k0 + 128 < K) STAGE(k0 + 128, 0);
        COMPUTE(1);
    }
#undef STAGE
#undef COMPUTE

    // epilogue: C/D layout col=lane&15, row=(lane>>4)*4+reg (16x16 family)
    const int orow0 = bm + waveM + (lane >> 4) * 4;
    const int ocol0 = bn + waveN + fr;
#pragma unroll
    for (int j = 0; j < 4; ++j) {
        const int col = ocol0 + j * 16;
        const float wn = wsc[col];
        const float bv = bias[col];
#pragma unroll
        for (int i = 0; i < 4; ++i) {
            const int rbase = orow0 + i * 16;
#pragma unroll
            for (int r = 0; r < 4; ++r) {
                const int row = rbase + r;
                float v = (float)acc[i][j][r] * xs[row];
                out[(size_t)row * N + col] = v * wn + bv;
            }
        }
    }
}

extern "C" void kernel_launch(void* const* d_in, const int* in_sizes, int n_in,
                              void* d_out, int out_size, void* d_ws, size_t ws_size,
                              hipStream_t stream) {
    const float* x    = (const float*)d_in[0];
    const float* w    = (const float*)d_in[1];
    const float* bias = (const float*)d_in[2];
    float* out = (float*)d_out;

    const int N = in_sizes[2];            // 1024
    const int K = in_sizes[1] / N;        // 1024
    const int M = in_sizes[0] / K;        // 32768

    char* ws = (char*)d_ws;
    float* p1x       = (float*)(ws);                    // 1024 x K  (4 MB)
    float* p2x       = (float*)(ws + 4194304);          // 16 x K    (64 KB)
    float* pw        = (float*)(ws + 4259840);          // 16 x K    (64 KB)
    float* smooth    = (float*)(ws + 4325376);          // K
    float* inv_s     = (float*)(ws + 4329472);          // K
    float* w_s       = (float*)(ws + 4333568);          // N
    float* x_s       = (float*)(ws + 4337664);          // M  (128 KB)
    signed char* x_q = (signed char*)(ws + 4468736);    // M*K (32 MB)
    signed char* w_q = x_q + (size_t)M * K;             // N*K (1 MB)

    // stage-1 col abs-max of x: 1024 blocks x 32 rows (latency hiding)
    colmax_part_kernel<<<1024, 256, 0, stream>>>(x, M, 32, K, p1x);
    // stage-2: reduce 1024 partial rows -> 16
    colmax_part_kernel<<<16, 256, 0, stream>>>(p1x, 1024, 64, K, p2x);
    // col abs-max of w: 16 blocks x 64 rows
    colmax_part_kernel<<<16, 256, 0, stream>>>(w, N, 64, K, pw);
    // smooth scales
    finalize_kernel<<<(K + 255) / 256, 256, 0, stream>>>(p2x, 16, pw, 16, smooth, inv_s, K);
    // quantize weights (N rows) and activations (M rows), one wave per row
    quant_rows_wave_kernel<<<N / 4, 256, 0, stream>>>(w, smooth, w_q, w_s, K);
    quant_rows_wave_kernel<<<M / 4, 256, 0, stream>>>(x, inv_s, x_q, x_s, K);
    // GEMM
    gemm_i8_kernel<<<(M / 128) * (N / 128), 256, 0, stream>>>(x_q, w_q, x_s, w_s, bias, out, M, N, K);
}